// Round 8
// baseline (441.528 us; speedup 1.0000x reference)
//
#include <hip/hip_runtime.h>
#include <hip/hip_fp16.h>
#include <stdint.h>

typedef _Float16 f16x8 __attribute__((ext_vector_type(8)));
typedef _Float16 f16x2 __attribute__((ext_vector_type(2)));
typedef float f32x4 __attribute__((ext_vector_type(4)));

#define BM 128
#define BN 128
#define BK 64

// ---------- async global->LDS, 16B per lane (wave-uniform LDS base + lane*16) ----------
__device__ __forceinline__ void async_copy16(const void* g, void* l) {
  __builtin_amdgcn_global_load_lds(
      (__attribute__((address_space(1))) void*)(g),
      (__attribute__((address_space(3))) void*)(l),
      16, 0, 0);
}

// ---------- fp32 -> fp16 conversion (W only now: 1M elements) ----------
__global__ __launch_bounds__(256) void cvt_f32_f16(const float* __restrict__ in,
                                                   _Float16* __restrict__ out,
                                                   size_t n) {
  size_t i = ((size_t)blockIdx.x * 256 + threadIdx.x) * 8;
  if (i + 8 > n) return;
  float4 u = *(const float4*)(in + i);
  float4 v = *(const float4*)(in + i + 4);
  f16x8 h;
  h[0] = (_Float16)u.x; h[1] = (_Float16)u.y; h[2] = (_Float16)u.z; h[3] = (_Float16)u.w;
  h[4] = (_Float16)v.x; h[5] = (_Float16)v.y; h[6] = (_Float16)v.z; h[7] = (_Float16)v.w;
  *(f16x8*)(out + i) = h;
}

// ---------- direct GEMM: H = A[M,K](fp32!) * W[N,K]^T(fp16) + bias; fused stats ----------
// A is converted fp32->fp16 IN-REGISTER during staging (kills the 198MB cvt-A pass and
// 64MB of ws): global reads stay linear/coalesced, the XOR swizzle moves to the LDS
// destination address of ds_write_b128. W keeps global_load_lds (2MB, L2-resident).
// Verified invariants: XOR swizzle (R4: conflicts 2.5e7->0), XCD remap (R5: FETCH
// 266->65MB), H2 pair-interleaved fp16 stores (R6: WRITE 102->70MB), [slot][c] partials.
template <bool H16>
__global__ __launch_bounds__(256) void gemm_a32(const float* __restrict__ Af,
                                                const _Float16* __restrict__ Wh,
                                                const float* __restrict__ bias,
                                                void* __restrict__ Hout,
                                                float* __restrict__ psum,
                                                float* __restrict__ psumsq,
                                                int M, int N, int K) {
  __shared__ __attribute__((aligned(16))) _Float16 lsA[BM * BK];
  __shared__ __attribute__((aligned(16))) _Float16 lsB[BN * BK];

  const int tid  = threadIdx.x;
  const int wave = tid >> 6;
  const int lane = tid & 63;
  const int wrow = (wave >> 1) * 64;
  const int wcol = (wave & 1) * 64;
  const int l16  = lane & 15;
  const int quad = lane >> 4;

  // XCD-aware remap: same-bm blocks share an XCD
  const int nx = gridDim.x;
  const int li = blockIdx.y * nx + blockIdx.x;
  const int xcd = li & 7;
  const int jj  = li >> 3;
  const int bnT = jj % nx;
  const int bmT = xcd + (jj / nx) * 8;
  const int bm = bmT * BM;
  const int bn = bnT * BN;

  f32x4 acc[4][4];
#pragma unroll
  for (int i = 0; i < 4; ++i)
#pragma unroll
    for (int j = 0; j < 4; ++j) acc[i][j] = (f32x4){0.f, 0.f, 0.f, 0.f};

  for (int k0 = 0; k0 < K; k0 += BK) {
    // ---- B (weights) via async global_load_lds, source-swizzled ----
#pragma unroll
    for (int i = 0; i < 4; ++i) {
      const int basechunk = i * 256 + wave * 64;    // wave-uniform LDS base
      const int g   = basechunk + lane;
      const int row = g >> 3;
      const int kc  = ((g & 7) ^ (row & 7)) << 3;
      async_copy16(Wh + (size_t)(bn + row) * K + k0 + kc, &lsB[basechunk * 8]);
    }
    // ---- A (activations) fp32 load + in-register cvt, dest-swizzled ds_write ----
#pragma unroll
    for (int i = 0; i < 4; ++i) {
      const int g   = i * 256 + tid;
      const int row = g >> 3;
      const int kc8 = g & 7;
      const float* src = Af + (size_t)(bm + row) * K + k0 + kc8 * 8;
      float4 u = *(const float4*)src;
      float4 v = *(const float4*)(src + 4);
      f16x8 h;
      h[0] = (_Float16)u.x; h[1] = (_Float16)u.y; h[2] = (_Float16)u.z; h[3] = (_Float16)u.w;
      h[4] = (_Float16)v.x; h[5] = (_Float16)v.y; h[6] = (_Float16)v.z; h[7] = (_Float16)v.w;
      const int slot = row * 8 + (kc8 ^ (row & 7));
      *(f16x8*)&lsA[slot * 8] = h;
    }
    __syncthreads();

#pragma unroll
    for (int kk = 0; kk < BK; kk += 32) {
      f16x8 af[4], bf[4];
#pragma unroll
      for (int i = 0; i < 4; ++i) {
        const int r = wrow + i * 16 + l16;
        const int col = ((kk >> 3) + quad) ^ (l16 & 7);
        af[i] = *(const f16x8*)&lsA[r * 64 + col * 8];
      }
#pragma unroll
      for (int j = 0; j < 4; ++j) {
        const int r = wcol + j * 16 + l16;
        const int col = ((kk >> 3) + quad) ^ (l16 & 7);
        bf[j] = *(const f16x8*)&lsB[r * 64 + col * 8];
      }
#pragma unroll
      for (int i = 0; i < 4; ++i)
#pragma unroll
        for (int j = 0; j < 4; ++j)
          acc[i][j] = __builtin_amdgcn_mfma_f32_16x16x32_f16(af[i], bf[j], acc[i][j], 0, 0, 0);
    }
    __syncthreads();
  }

  // ---- epilogue: H write (+bias) and per-column partial stats ----
#pragma unroll
  for (int j = 0; j < 4; ++j) {
    const int c = bn + wcol + j * 16 + l16;
    const float bv = bias[c];
    float s = 0.f, s2 = 0.f;
#pragma unroll
    for (int i = 0; i < 4; ++i) {
      const int r = bm + wrow + i * 16 + quad * 4;   // always even
      f32x4 v = acc[i][j];
      const float v0 = v[0] + bv, v1 = v[1] + bv, v2 = v[2] + bv, v3 = v[3] + bv;
      s += v0 + v1 + v2 + v3;
      s2 += v0 * v0 + v1 * v1 + v2 * v2 + v3 * v3;
      if constexpr (H16) {
        f16x2* H2 = (f16x2*)Hout;
        const size_t d0 = (size_t)(r >> 1) * N + c;
        H2[d0]     = (f16x2){(_Float16)v0, (_Float16)v1};
        H2[d0 + N] = (f16x2){(_Float16)v2, (_Float16)v3};
      } else {
        float* Cp = (float*)Hout + (size_t)r * N + c;
        Cp[0] = v0; Cp[(size_t)N] = v1; Cp[2 * (size_t)N] = v2; Cp[3 * (size_t)N] = v3;
      }
    }
    s  += __shfl_xor(s, 16, 64);  s  += __shfl_xor(s, 32, 64);
    s2 += __shfl_xor(s2, 16, 64); s2 += __shfl_xor(s2, 32, 64);
    if (quad == 0) {
      const size_t slot = (size_t)(bmT * 2 + (wave >> 1)) * N + c;  // [slot][c]
      psum[slot] = s;
      psumsq[slot] = s2;
    }
  }
}

// ---------- fallback GEMM (fp32 inputs, in-register cvt both, atomic stats) ----------
__global__ __launch_bounds__(256) void gemm_fallback(const float* __restrict__ Af,
                                                     const float* __restrict__ Wf,
                                                     const float* __restrict__ bias,
                                                     float* __restrict__ C,
                                                     float* __restrict__ sum,
                                                     float* __restrict__ sumsq,
                                                     int M, int N, int K) {
  __shared__ __attribute__((aligned(16))) _Float16 lsA[BM * BK];
  __shared__ __attribute__((aligned(16))) _Float16 lsB[BN * BK];
  const int tid  = threadIdx.x;
  const int wave = tid >> 6;
  const int lane = tid & 63;
  const int wrow = (wave >> 1) * 64;
  const int wcol = (wave & 1) * 64;
  const int l16  = lane & 15;
  const int quad = lane >> 4;
  const int bm = blockIdx.y * BM;
  const int bn = blockIdx.x * BN;

  f32x4 acc[4][4];
#pragma unroll
  for (int i = 0; i < 4; ++i)
#pragma unroll
    for (int j = 0; j < 4; ++j) acc[i][j] = (f32x4){0.f, 0.f, 0.f, 0.f};

  for (int k0 = 0; k0 < K; k0 += BK) {
#pragma unroll
    for (int i = 0; i < 4; ++i) {
      const int g   = i * 256 + tid;
      const int row = g >> 3;
      const int kc8 = g & 7;
      const int slot = row * 8 + (kc8 ^ (row & 7));
      {
        const float* src = Af + (size_t)(bm + row) * K + k0 + kc8 * 8;
        float4 u = *(const float4*)src;
        float4 v = *(const float4*)(src + 4);
        f16x8 h;
        h[0] = (_Float16)u.x; h[1] = (_Float16)u.y; h[2] = (_Float16)u.z; h[3] = (_Float16)u.w;
        h[4] = (_Float16)v.x; h[5] = (_Float16)v.y; h[6] = (_Float16)v.z; h[7] = (_Float16)v.w;
        *(f16x8*)&lsA[slot * 8] = h;
      }
      {
        const float* src = Wf + (size_t)(bn + row) * K + k0 + kc8 * 8;
        float4 u = *(const float4*)src;
        float4 v = *(const float4*)(src + 4);
        f16x8 h;
        h[0] = (_Float16)u.x; h[1] = (_Float16)u.y; h[2] = (_Float16)u.z; h[3] = (_Float16)u.w;
        h[4] = (_Float16)v.x; h[5] = (_Float16)v.y; h[6] = (_Float16)v.z; h[7] = (_Float16)v.w;
        *(f16x8*)&lsB[slot * 8] = h;
      }
    }
    __syncthreads();
#pragma unroll
    for (int kk = 0; kk < BK; kk += 32) {
      f16x8 af[4], bf[4];
#pragma unroll
      for (int i = 0; i < 4; ++i) {
        const int r = wrow + i * 16 + l16;
        const int col = ((kk >> 3) + quad) ^ (l16 & 7);
        af[i] = *(const f16x8*)&lsA[r * 64 + col * 8];
      }
#pragma unroll
      for (int j = 0; j < 4; ++j) {
        const int r = wcol + j * 16 + l16;
        const int col = ((kk >> 3) + quad) ^ (l16 & 7);
        bf[j] = *(const f16x8*)&lsB[r * 64 + col * 8];
      }
#pragma unroll
      for (int i = 0; i < 4; ++i)
#pragma unroll
        for (int j = 0; j < 4; ++j)
          acc[i][j] = __builtin_amdgcn_mfma_f32_16x16x32_f16(af[i], bf[j], acc[i][j], 0, 0, 0);
    }
    __syncthreads();
  }

#pragma unroll
  for (int j = 0; j < 4; ++j) {
    const int c = bn + wcol + j * 16 + l16;
    const float bv = bias[c];
    float s = 0.f, s2 = 0.f;
#pragma unroll
    for (int i = 0; i < 4; ++i) {
      const int r = bm + wrow + i * 16 + quad * 4;
      float* Cp = C + (size_t)r * N + c;
      f32x4 v = acc[i][j];
#pragma unroll
      for (int rr = 0; rr < 4; ++rr) {
        float val = v[rr] + bv;
        Cp[(size_t)rr * N] = val;
        s += val;
        s2 += val * val;
      }
    }
    s  += __shfl_xor(s, 16, 64);  s  += __shfl_xor(s, 32, 64);
    s2 += __shfl_xor(s2, 16, 64); s2 += __shfl_xor(s2, 32, 64);
    if (quad == 0) {
      atomicAdd(&sum[c], s);
      atomicAdd(&sumsq[c], s2);
    }
  }
}

// ---------- finalize from [slot][c] partials: one wave per column ----------
__global__ __launch_bounds__(256) void bn_finalize_wave(const float* __restrict__ psum,
                                                        const float* __restrict__ psumsq,
                                                        const float* __restrict__ gamma,
                                                        const float* __restrict__ beta,
                                                        float* __restrict__ scale,
                                                        float* __restrict__ shift,
                                                        float invB, int S, int D) {
  const int wave = threadIdx.x >> 6;
  const int lane = threadIdx.x & 63;
  const int c = blockIdx.x * 4 + wave;
  float s = 0.f, q = 0.f;
  for (int u = lane; u < S; u += 64) {
    s += psum[(size_t)u * D + c];
    q += psumsq[(size_t)u * D + c];
  }
#pragma unroll
  for (int o = 32; o > 0; o >>= 1) {
    s += __shfl_xor(s, o, 64);
    q += __shfl_xor(q, o, 64);
  }
  if (lane == 0) {
    float mean = s * invB;
    float var  = q * invB - mean * mean;
    float rstd = rsqrtf(var + 1e-5f);
    float sc = rstd * gamma[c];
    scale[c] = sc;
    shift[c] = beta[c] - mean * sc;
  }
}

// ---------- finalize from atomic sums (fallback) ----------
__global__ __launch_bounds__(256) void bn_finalize(const float* __restrict__ sum,
                                                   const float* __restrict__ sumsq,
                                                   const float* __restrict__ gamma,
                                                   const float* __restrict__ beta,
                                                   float* __restrict__ scale,
                                                   float* __restrict__ shift,
                                                   float invB) {
  const int c = blockIdx.x * 256 + threadIdx.x;
  float mean = sum[c] * invB;
  float var  = sumsq[c] * invB - mean * mean;
  float rstd = rsqrtf(var + 1e-5f);
  float sc = rstd * gamma[c];
  scale[c] = sc;
  shift[c] = beta[c] - mean * sc;
}

// ---------- BN + prior + sparsemax: one row per wave, H2 pair-interleaved fp16 ----------
__global__ __launch_bounds__(256) void bn_sparsemax_h2(const _Float16* __restrict__ H2,
                                                       const float* __restrict__ P,
                                                       const float* __restrict__ scale,
                                                       const float* __restrict__ shift,
                                                       float* __restrict__ out, int D) {
  const int wave = threadIdx.x >> 6;
  const int lane = threadIdx.x & 63;
  const int row = blockIdx.x * 4 + wave;
  const int rp  = row >> 1;
  const int par = row & 1;

  const f16x8* Hc = (const f16x8*)(H2 + (size_t)rp * 2 * D);
  const f32x4* P4 = (const f32x4*)(P + (size_t)row * D);
  const f32x4* SC = (const f32x4*)scale;
  const f32x4* SH = (const f32x4*)shift;

  f32x4 z[4];
  float tot = 0.f;
#pragma unroll
  for (int j = 0; j < 4; ++j) {
    const int idx = j * 64 + lane;
    f16x8 h = Hc[idx];
    f32x4 hv = {(float)h[par], (float)h[2 + par], (float)h[4 + par], (float)h[6 + par]};
    f32x4 zz = P4[idx] * (hv * SC[idx] + SH[idx]);
    z[j] = zz;
    tot += zz[0] + zz[1] + zz[2] + zz[3];
  }
#pragma unroll
  for (int o = 32; o > 0; o >>= 1) tot += __shfl_xor(tot, o, 64);

  float tau = (tot - 1.0f) / (float)D;
  float kprev = -1.0f;
  for (int it = 0; it < 64; ++it) {
    float s = 0.f, kf = 0.f;
#pragma unroll
    for (int j = 0; j < 4; ++j)
#pragma unroll
      for (int c = 0; c < 4; ++c) {
        float zz = z[j][c];
        if (zz > tau) { s += zz; kf += 1.0f; }
      }
#pragma unroll
    for (int o = 32; o > 0; o >>= 1) {
      s  += __shfl_xor(s, o, 64);
      kf += __shfl_xor(kf, o, 64);
    }
    tau = (s - 1.0f) / kf;
    if (kf == kprev) break;
    kprev = kf;
  }

  f32x4* O4 = (f32x4*)(out + (size_t)row * D);
#pragma unroll
  for (int j = 0; j < 4; ++j) {
    const int idx = j * 64 + lane;
    f32x4 o;
#pragma unroll
    for (int c = 0; c < 4; ++c) o[c] = fmaxf(z[j][c] - tau, 0.f);
    O4[idx] = o;
  }
}

// ---------- fp32 row-major variant (fallback path) ----------
__global__ __launch_bounds__(256) void bn_sparsemax_f32(const float* __restrict__ H,
                                                        const float* __restrict__ P,
                                                        const float* __restrict__ scale,
                                                        const float* __restrict__ shift,
                                                        float* __restrict__ out, int D) {
  const int wave = threadIdx.x >> 6;
  const int lane = threadIdx.x & 63;
  const int row = blockIdx.x * 4 + wave;
  const size_t rowoff = (size_t)row * D;
  const f32x4* H4 = (const f32x4*)(H + rowoff);
  const f32x4* P4 = (const f32x4*)(P + rowoff);
  const f32x4* SC = (const f32x4*)scale;
  const f32x4* SH = (const f32x4*)shift;

  f32x4 z[4];
  float tot = 0.f;
#pragma unroll
  for (int j = 0; j < 4; ++j) {
    const int idx = j * 64 + lane;
    f32x4 zz = P4[idx] * (H4[idx] * SC[idx] + SH[idx]);
    z[j] = zz;
    tot += zz[0] + zz[1] + zz[2] + zz[3];
  }
#pragma unroll
  for (int o = 32; o > 0; o >>= 1) tot += __shfl_xor(tot, o, 64);

  float tau = (tot - 1.0f) / (float)D;
  float kprev = -1.0f;
  for (int it = 0; it < 64; ++it) {
    float s = 0.f, kf = 0.f;
#pragma unroll
    for (int j = 0; j < 4; ++j)
#pragma unroll
      for (int c = 0; c < 4; ++c) {
        float zz = z[j][c];
        if (zz > tau) { s += zz; kf += 1.0f; }
      }
#pragma unroll
    for (int o = 32; o > 0; o >>= 1) {
      s  += __shfl_xor(s, o, 64);
      kf += __shfl_xor(kf, o, 64);
    }
    tau = (s - 1.0f) / kf;
    if (kf == kprev) break;
    kprev = kf;
  }

  f32x4* O4 = (f32x4*)(out + rowoff);
#pragma unroll
  for (int j = 0; j < 4; ++j) {
    const int idx = j * 64 + lane;
    f32x4 o;
#pragma unroll
    for (int c = 0; c < 4; ++c) o[c] = fmaxf(z[j][c] - tau, 0.f);
    O4[idx] = o;
  }
}

extern "C" void kernel_launch(void* const* d_in, const int* in_sizes, int n_in,
                              void* d_out, int out_size, void* d_ws, size_t ws_size,
                              hipStream_t stream) {
  const float* a     = (const float*)d_in[0];
  const float* p     = (const float*)d_in[1];
  const float* W     = (const float*)d_in[2];
  const float* b     = (const float*)d_in[3];
  const float* gamma = (const float*)d_in[4];
  const float* beta  = (const float*)d_in[5];
  float* out = (float*)d_out;

  const int D = in_sizes[3];           // 1024
  const int Brows = in_sizes[0] / D;   // 32768
  const int K = D, N = D;
  const size_t na = (size_t)Brows * D;
  const size_t nw = (size_t)D * D;
  const int S = (Brows / BM) * 2;      // partial slots (512)

  // ws layout (~70 MB): [psum S*D][psumsq S*D][scale D][shift D][Wh fp16][H2 fp16]
  const size_t statsB = (size_t)D * S * sizeof(float);           // 2 MB
  float* psum   = (float*)d_ws;
  float* psumsq = (float*)((char*)d_ws + statsB);
  float* wscale = (float*)((char*)d_ws + 2 * statsB);
  float* wshift = wscale + D;
  const size_t off_Wh = 2 * statsB + 16384;
  _Float16* Wh = (_Float16*)((char*)d_ws + off_Wh);
  _Float16* H2 = Wh + nw;
  const size_t need_h16 = off_Wh + (nw + na) * sizeof(_Float16); // ~70 MB
  const size_t need_w   = off_Wh + nw * sizeof(_Float16);        // ~6 MB

  if (ws_size >= need_h16) {
    cvt_f32_f16<<<dim3((unsigned)(nw / 8 / 256)), 256, 0, stream>>>(W, Wh, nw);
    gemm_a32<true><<<dim3(N / BN, Brows / BM), 256, 0, stream>>>(
        a, Wh, b, H2, psum, psumsq, Brows, N, K);
    bn_finalize_wave<<<dim3(D / 4), 256, 0, stream>>>(psum, psumsq, gamma, beta,
                                                      wscale, wshift,
                                                      1.0f / (float)Brows, S, D);
    bn_sparsemax_h2<<<dim3(Brows / 4), 256, 0, stream>>>(H2, p, wscale, wshift, out, D);
  } else if (ws_size >= need_w) {
    // mid-ws: H fp32 lives in d_out
    cvt_f32_f16<<<dim3((unsigned)(nw / 8 / 256)), 256, 0, stream>>>(W, Wh, nw);
    gemm_a32<false><<<dim3(N / BN, Brows / BM), 256, 0, stream>>>(
        a, Wh, b, out, psum, psumsq, Brows, N, K);
    bn_finalize_wave<<<dim3(D / 4), 256, 0, stream>>>(psum, psumsq, gamma, beta,
                                                      wscale, wshift,
                                                      1.0f / (float)Brows, S, D);
    bn_sparsemax_f32<<<dim3(Brows / 4), 256, 0, stream>>>(out, p, wscale, wshift, out, D);
  } else {
    // tiny-ws fallback: atomic stats, fp32 H in d_out, in-register cvt of A and W
    float* wsum   = (float*)d_ws;
    float* wsumsq = wsum + D;
    float* fscale = wsum + 2 * D;
    float* fshift = wsum + 3 * D;
    hipMemsetAsync(d_ws, 0, 2 * D * sizeof(float), stream);
    gemm_fallback<<<dim3(N / BN, Brows / BM), 256, 0, stream>>>(
        a, W, b, out, wsum, wsumsq, Brows, N, K);
    bn_finalize<<<dim3(D / 256), 256, 0, stream>>>(wsum, wsumsq, gamma, beta, fscale, fshift,
                                                   1.0f / (float)Brows);
    bn_sparsemax_f32<<<dim3(Brows / 4), 256, 0, stream>>>(out, p, fscale, fshift, out, D);
  }
}

// Round 9
// 418.041 us; speedup vs baseline: 1.0562x; 1.0562x over previous
//
#include <hip/hip_runtime.h>
#include <hip/hip_fp16.h>
#include <stdint.h>

typedef _Float16 f16x8 __attribute__((ext_vector_type(8)));
typedef _Float16 f16x2 __attribute__((ext_vector_type(2)));
typedef float f32x4 __attribute__((ext_vector_type(4)));

#define BM 128
#define BN 128
#define BK 64

// ---------- async global->LDS, 16B per lane (wave-uniform LDS base + lane*16) ----------
__device__ __forceinline__ void async_copy16(const void* g, void* l) {
  __builtin_amdgcn_global_load_lds(
      (__attribute__((address_space(1))) void*)(g),
      (__attribute__((address_space(3))) void*)(l),
      16, 0, 0);
}

// ---------- fp32 -> fp16 conversion (W only: 1M elements, ~4 us) ----------
__global__ __launch_bounds__(256) void cvt_f32_f16(const float* __restrict__ in,
                                                   _Float16* __restrict__ out,
                                                   size_t n) {
  size_t i = ((size_t)blockIdx.x * 256 + threadIdx.x) * 8;
  if (i + 8 > n) return;
  float4 u = *(const float4*)(in + i);
  float4 v = *(const float4*)(in + i + 4);
  f16x8 h;
  h[0] = (_Float16)u.x; h[1] = (_Float16)u.y; h[2] = (_Float16)u.z; h[3] = (_Float16)u.w;
  h[4] = (_Float16)v.x; h[5] = (_Float16)v.y; h[6] = (_Float16)v.z; h[7] = (_Float16)v.w;
  *(f16x8*)(out + i) = h;
}

// ---------- GEMM: H = A[M,K](fp32, ASYNC-staged) * W[N,K]^T(fp16) + bias; fused stats ----------
// A is staged fp32 via global_load_lds (async DMA preserved — R8's sync staging cost +67us)
// into a 32KB LDS buffer, converted fp32->fp16 at FRAGMENT-READ time (2x ds_read_b128 +
// packed cvt). This deletes the 50us cvt-A pass while keeping the R7 GEMM structure.
// A-swizzle: LDS slot r*16 + (c ^ (r&15)) holds 4-float chunk c of row r -> each b128
// read hits every bank exactly 8 dwords = the wave64 floor (conflict-free).
// Verified invariants: B XOR swizzle (R4), XCD remap (R5: FETCH->ideal), H2
// pair-interleaved fp16 stores (R6: WRITE->ideal), [slot][c] stats partials (R5).
template <bool H16>
__global__ __launch_bounds__(256) void gemm_af32(const float* __restrict__ Af,
                                                 const _Float16* __restrict__ Wh,
                                                 const float* __restrict__ bias,
                                                 void* __restrict__ Hout,
                                                 float* __restrict__ psum,
                                                 float* __restrict__ psumsq,
                                                 int M, int N, int K) {
  __shared__ __attribute__((aligned(16))) float    lsA[BM * BK];   // 32 KB fp32
  __shared__ __attribute__((aligned(16))) _Float16 lsB[BN * BK];   // 16 KB fp16

  const int tid  = threadIdx.x;
  const int wave = tid >> 6;
  const int lane = tid & 63;
  const int wrow = (wave >> 1) * 64;
  const int wcol = (wave & 1) * 64;
  const int l16  = lane & 15;
  const int quad = lane >> 4;

  // XCD-aware remap: same-bm blocks share an XCD
  const int nx = gridDim.x;
  const int li = blockIdx.y * nx + blockIdx.x;
  const int xcd = li & 7;
  const int jj  = li >> 3;
  const int bnT = jj % nx;
  const int bmT = xcd + (jj / nx) * 8;
  const int bm = bmT * BM;
  const int bn = bnT * BN;

  f32x4 acc[4][4];
#pragma unroll
  for (int i = 0; i < 4; ++i)
#pragma unroll
    for (int j = 0; j < 4; ++j) acc[i][j] = (f32x4){0.f, 0.f, 0.f, 0.f};

  for (int k0 = 0; k0 < K; k0 += BK) {
    // ---- B (weights fp16): async, source-swizzled (chunk = 8 halves) ----
#pragma unroll
    for (int i = 0; i < 4; ++i) {
      const int basechunk = i * 256 + wave * 64;    // wave-uniform LDS base
      const int g   = basechunk + lane;
      const int row = g >> 3;
      const int kc  = ((g & 7) ^ (row & 7)) << 3;
      async_copy16(Wh + (size_t)(bn + row) * K + k0 + kc, &lsB[basechunk * 8]);
    }
    // ---- A (activations fp32): async, source-swizzled (chunk = 4 floats) ----
#pragma unroll
    for (int i = 0; i < 8; ++i) {
      const int basechunk = i * 256 + wave * 64;    // wave-uniform LDS base
      const int g   = basechunk + lane;             // slot index
      const int row = g >> 4;
      const int cc  = (g & 15) ^ (row & 15);        // swizzled source chunk
      async_copy16(Af + (size_t)(bm + row) * K + k0 + cc * 4, &lsA[basechunk * 4]);
    }
    __syncthreads();

#pragma unroll
    for (int kk = 0; kk < BK; kk += 32) {
      f16x8 af[4], bf[4];
#pragma unroll
      for (int i = 0; i < 4; ++i) {
        const int r = wrow + i * 16 + l16;
        const int c0 = (kk >> 2) + quad * 2;        // first 4-float chunk
        f32x4 a0 = *(const f32x4*)&lsA[(r * 16 + (c0 ^ (r & 15))) * 4];
        f32x4 a1 = *(const f32x4*)&lsA[(r * 16 + ((c0 + 1) ^ (r & 15))) * 4];
        f16x8 h;
        h[0] = (_Float16)a0[0]; h[1] = (_Float16)a0[1];
        h[2] = (_Float16)a0[2]; h[3] = (_Float16)a0[3];
        h[4] = (_Float16)a1[0]; h[5] = (_Float16)a1[1];
        h[6] = (_Float16)a1[2]; h[7] = (_Float16)a1[3];
        af[i] = h;
      }
#pragma unroll
      for (int j = 0; j < 4; ++j) {
        const int r = wcol + j * 16 + l16;
        const int col = ((kk >> 3) + quad) ^ (l16 & 7);
        bf[j] = *(const f16x8*)&lsB[r * 64 + col * 8];
      }
#pragma unroll
      for (int i = 0; i < 4; ++i)
#pragma unroll
        for (int j = 0; j < 4; ++j)
          acc[i][j] = __builtin_amdgcn_mfma_f32_16x16x32_f16(af[i], bf[j], acc[i][j], 0, 0, 0);
    }
    __syncthreads();
  }

  // ---- epilogue: H write (+bias) and per-column partial stats ----
#pragma unroll
  for (int j = 0; j < 4; ++j) {
    const int c = bn + wcol + j * 16 + l16;
    const float bv = bias[c];
    float s = 0.f, s2 = 0.f;
#pragma unroll
    for (int i = 0; i < 4; ++i) {
      const int r = bm + wrow + i * 16 + quad * 4;   // always even
      f32x4 v = acc[i][j];
      const float v0 = v[0] + bv, v1 = v[1] + bv, v2 = v[2] + bv, v3 = v[3] + bv;
      s += v0 + v1 + v2 + v3;
      s2 += v0 * v0 + v1 * v1 + v2 * v2 + v3 * v3;
      if constexpr (H16) {
        f16x2* H2 = (f16x2*)Hout;
        const size_t d0 = (size_t)(r >> 1) * N + c;
        H2[d0]     = (f16x2){(_Float16)v0, (_Float16)v1};
        H2[d0 + N] = (f16x2){(_Float16)v2, (_Float16)v3};
      } else {
        float* Cp = (float*)Hout + (size_t)r * N + c;
        Cp[0] = v0; Cp[(size_t)N] = v1; Cp[2 * (size_t)N] = v2; Cp[3 * (size_t)N] = v3;
      }
    }
    s  += __shfl_xor(s, 16, 64);  s  += __shfl_xor(s, 32, 64);
    s2 += __shfl_xor(s2, 16, 64); s2 += __shfl_xor(s2, 32, 64);
    if (quad == 0) {
      const size_t slot = (size_t)(bmT * 2 + (wave >> 1)) * N + c;  // [slot][c]
      psum[slot] = s;
      psumsq[slot] = s2;
    }
  }
}

// ---------- fallback GEMM (fp32 inputs, in-register cvt both, atomic stats) ----------
__global__ __launch_bounds__(256) void gemm_fallback(const float* __restrict__ Af,
                                                     const float* __restrict__ Wf,
                                                     const float* __restrict__ bias,
                                                     float* __restrict__ C,
                                                     float* __restrict__ sum,
                                                     float* __restrict__ sumsq,
                                                     int M, int N, int K) {
  __shared__ __attribute__((aligned(16))) _Float16 lsA[BM * BK];
  __shared__ __attribute__((aligned(16))) _Float16 lsB[BN * BK];
  const int tid  = threadIdx.x;
  const int wave = tid >> 6;
  const int lane = tid & 63;
  const int wrow = (wave >> 1) * 64;
  const int wcol = (wave & 1) * 64;
  const int l16  = lane & 15;
  const int quad = lane >> 4;
  const int bm = blockIdx.y * BM;
  const int bn = blockIdx.x * BN;

  f32x4 acc[4][4];
#pragma unroll
  for (int i = 0; i < 4; ++i)
#pragma unroll
    for (int j = 0; j < 4; ++j) acc[i][j] = (f32x4){0.f, 0.f, 0.f, 0.f};

  for (int k0 = 0; k0 < K; k0 += BK) {
#pragma unroll
    for (int i = 0; i < 4; ++i) {
      const int g   = i * 256 + tid;
      const int row = g >> 3;
      const int kc8 = g & 7;
      const int slot = row * 8 + (kc8 ^ (row & 7));
      {
        const float* src = Af + (size_t)(bm + row) * K + k0 + kc8 * 8;
        float4 u = *(const float4*)src;
        float4 v = *(const float4*)(src + 4);
        f16x8 h;
        h[0] = (_Float16)u.x; h[1] = (_Float16)u.y; h[2] = (_Float16)u.z; h[3] = (_Float16)u.w;
        h[4] = (_Float16)v.x; h[5] = (_Float16)v.y; h[6] = (_Float16)v.z; h[7] = (_Float16)v.w;
        *(f16x8*)&lsA[slot * 8] = h;
      }
      {
        const float* src = Wf + (size_t)(bn + row) * K + k0 + kc8 * 8;
        float4 u = *(const float4*)src;
        float4 v = *(const float4*)(src + 4);
        f16x8 h;
        h[0] = (_Float16)u.x; h[1] = (_Float16)u.y; h[2] = (_Float16)u.z; h[3] = (_Float16)u.w;
        h[4] = (_Float16)v.x; h[5] = (_Float16)v.y; h[6] = (_Float16)v.z; h[7] = (_Float16)v.w;
        *(f16x8*)&lsB[slot * 8] = h;
      }
    }
    __syncthreads();
#pragma unroll
    for (int kk = 0; kk < BK; kk += 32) {
      f16x8 af[4], bf[4];
#pragma unroll
      for (int i = 0; i < 4; ++i) {
        const int r = wrow + i * 16 + l16;
        const int col = ((kk >> 3) + quad) ^ (l16 & 7);
        af[i] = *(const f16x8*)&lsA[r * 64 + col * 8];
      }
#pragma unroll
      for (int j = 0; j < 4; ++j) {
        const int r = wcol + j * 16 + l16;
        const int col = ((kk >> 3) + quad) ^ (l16 & 7);
        bf[j] = *(const f16x8*)&lsB[r * 64 + col * 8];
      }
#pragma unroll
      for (int i = 0; i < 4; ++i)
#pragma unroll
        for (int j = 0; j < 4; ++j)
          acc[i][j] = __builtin_amdgcn_mfma_f32_16x16x32_f16(af[i], bf[j], acc[i][j], 0, 0, 0);
    }
    __syncthreads();
  }

#pragma unroll
  for (int j = 0; j < 4; ++j) {
    const int c = bn + wcol + j * 16 + l16;
    const float bv = bias[c];
    float s = 0.f, s2 = 0.f;
#pragma unroll
    for (int i = 0; i < 4; ++i) {
      const int r = bm + wrow + i * 16 + quad * 4;
      float* Cp = C + (size_t)r * N + c;
      f32x4 v = acc[i][j];
#pragma unroll
      for (int rr = 0; rr < 4; ++rr) {
        float val = v[rr] + bv;
        Cp[(size_t)rr * N] = val;
        s += val;
        s2 += val * val;
      }
    }
    s  += __shfl_xor(s, 16, 64);  s  += __shfl_xor(s, 32, 64);
    s2 += __shfl_xor(s2, 16, 64); s2 += __shfl_xor(s2, 32, 64);
    if (quad == 0) {
      atomicAdd(&sum[c], s);
      atomicAdd(&sumsq[c], s2);
    }
  }
}

// ---------- finalize from [slot][c] partials: one wave per column ----------
__global__ __launch_bounds__(256) void bn_finalize_wave(const float* __restrict__ psum,
                                                        const float* __restrict__ psumsq,
                                                        const float* __restrict__ gamma,
                                                        const float* __restrict__ beta,
                                                        float* __restrict__ scale,
                                                        float* __restrict__ shift,
                                                        float invB, int S, int D) {
  const int wave = threadIdx.x >> 6;
  const int lane = threadIdx.x & 63;
  const int c = blockIdx.x * 4 + wave;
  float s = 0.f, q = 0.f;
  for (int u = lane; u < S; u += 64) {
    s += psum[(size_t)u * D + c];
    q += psumsq[(size_t)u * D + c];
  }
#pragma unroll
  for (int o = 32; o > 0; o >>= 1) {
    s += __shfl_xor(s, o, 64);
    q += __shfl_xor(q, o, 64);
  }
  if (lane == 0) {
    float mean = s * invB;
    float var  = q * invB - mean * mean;
    float rstd = rsqrtf(var + 1e-5f);
    float sc = rstd * gamma[c];
    scale[c] = sc;
    shift[c] = beta[c] - mean * sc;
  }
}

// ---------- finalize from atomic sums (fallback) ----------
__global__ __launch_bounds__(256) void bn_finalize(const float* __restrict__ sum,
                                                   const float* __restrict__ sumsq,
                                                   const float* __restrict__ gamma,
                                                   const float* __restrict__ beta,
                                                   float* __restrict__ scale,
                                                   float* __restrict__ shift,
                                                   float invB) {
  const int c = blockIdx.x * 256 + threadIdx.x;
  float mean = sum[c] * invB;
  float var  = sumsq[c] * invB - mean * mean;
  float rstd = rsqrtf(var + 1e-5f);
  float sc = rstd * gamma[c];
  scale[c] = sc;
  shift[c] = beta[c] - mean * sc;
}

// ---------- BN + prior + sparsemax: one row per wave, H2 pair-interleaved fp16 ----------
__global__ __launch_bounds__(256) void bn_sparsemax_h2(const _Float16* __restrict__ H2,
                                                       const float* __restrict__ P,
                                                       const float* __restrict__ scale,
                                                       const float* __restrict__ shift,
                                                       float* __restrict__ out, int D) {
  const int wave = threadIdx.x >> 6;
  const int lane = threadIdx.x & 63;
  const int row = blockIdx.x * 4 + wave;
  const int rp  = row >> 1;
  const int par = row & 1;

  const f16x8* Hc = (const f16x8*)(H2 + (size_t)rp * 2 * D);
  const f32x4* P4 = (const f32x4*)(P + (size_t)row * D);
  const f32x4* SC = (const f32x4*)scale;
  const f32x4* SH = (const f32x4*)shift;

  f32x4 z[4];
  float tot = 0.f;
#pragma unroll
  for (int j = 0; j < 4; ++j) {
    const int idx = j * 64 + lane;
    f16x8 h = Hc[idx];
    f32x4 hv = {(float)h[par], (float)h[2 + par], (float)h[4 + par], (float)h[6 + par]};
    f32x4 zz = P4[idx] * (hv * SC[idx] + SH[idx]);
    z[j] = zz;
    tot += zz[0] + zz[1] + zz[2] + zz[3];
  }
#pragma unroll
  for (int o = 32; o > 0; o >>= 1) tot += __shfl_xor(tot, o, 64);

  float tau = (tot - 1.0f) / (float)D;
  float kprev = -1.0f;
  for (int it = 0; it < 64; ++it) {
    float s = 0.f, kf = 0.f;
#pragma unroll
    for (int j = 0; j < 4; ++j)
#pragma unroll
      for (int c = 0; c < 4; ++c) {
        float zz = z[j][c];
        if (zz > tau) { s += zz; kf += 1.0f; }
      }
#pragma unroll
    for (int o = 32; o > 0; o >>= 1) {
      s  += __shfl_xor(s, o, 64);
      kf += __shfl_xor(kf, o, 64);
    }
    tau = (s - 1.0f) / kf;
    if (kf == kprev) break;
    kprev = kf;
  }

  f32x4* O4 = (f32x4*)(out + (size_t)row * D);
#pragma unroll
  for (int j = 0; j < 4; ++j) {
    const int idx = j * 64 + lane;
    f32x4 o;
#pragma unroll
    for (int c = 0; c < 4; ++c) o[c] = fmaxf(z[j][c] - tau, 0.f);
    O4[idx] = o;
  }
}

// ---------- fp32 row-major variant (fallback path) ----------
__global__ __launch_bounds__(256) void bn_sparsemax_f32(const float* __restrict__ H,
                                                        const float* __restrict__ P,
                                                        const float* __restrict__ scale,
                                                        const float* __restrict__ shift,
                                                        float* __restrict__ out, int D) {
  const int wave = threadIdx.x >> 6;
  const int lane = threadIdx.x & 63;
  const int row = blockIdx.x * 4 + wave;
  const size_t rowoff = (size_t)row * D;
  const f32x4* H4 = (const f32x4*)(H + rowoff);
  const f32x4* P4 = (const f32x4*)(P + rowoff);
  const f32x4* SC = (const f32x4*)scale;
  const f32x4* SH = (const f32x4*)shift;

  f32x4 z[4];
  float tot = 0.f;
#pragma unroll
  for (int j = 0; j < 4; ++j) {
    const int idx = j * 64 + lane;
    f32x4 zz = P4[idx] * (H4[idx] * SC[idx] + SH[idx]);
    z[j] = zz;
    tot += zz[0] + zz[1] + zz[2] + zz[3];
  }
#pragma unroll
  for (int o = 32; o > 0; o >>= 1) tot += __shfl_xor(tot, o, 64);

  float tau = (tot - 1.0f) / (float)D;
  float kprev = -1.0f;
  for (int it = 0; it < 64; ++it) {
    float s = 0.f, kf = 0.f;
#pragma unroll
    for (int j = 0; j < 4; ++j)
#pragma unroll
      for (int c = 0; c < 4; ++c) {
        float zz = z[j][c];
        if (zz > tau) { s += zz; kf += 1.0f; }
      }
#pragma unroll
    for (int o = 32; o > 0; o >>= 1) {
      s  += __shfl_xor(s, o, 64);
      kf += __shfl_xor(kf, o, 64);
    }
    tau = (s - 1.0f) / kf;
    if (kf == kprev) break;
    kprev = kf;
  }

  f32x4* O4 = (f32x4*)(out + rowoff);
#pragma unroll
  for (int j = 0; j < 4; ++j) {
    const int idx = j * 64 + lane;
    f32x4 o;
#pragma unroll
    for (int c = 0; c < 4; ++c) o[c] = fmaxf(z[j][c] - tau, 0.f);
    O4[idx] = o;
  }
}

extern "C" void kernel_launch(void* const* d_in, const int* in_sizes, int n_in,
                              void* d_out, int out_size, void* d_ws, size_t ws_size,
                              hipStream_t stream) {
  const float* a     = (const float*)d_in[0];
  const float* p     = (const float*)d_in[1];
  const float* W     = (const float*)d_in[2];
  const float* b     = (const float*)d_in[3];
  const float* gamma = (const float*)d_in[4];
  const float* beta  = (const float*)d_in[5];
  float* out = (float*)d_out;

  const int D = in_sizes[3];           // 1024
  const int Brows = in_sizes[0] / D;   // 32768
  const int K = D, N = D;
  const size_t na = (size_t)Brows * D;
  const size_t nw = (size_t)D * D;
  const int S = (Brows / BM) * 2;      // partial slots (512)

  // ws layout (~70 MB): [psum S*D][psumsq S*D][scale D][shift D][Wh fp16][H2 fp16]
  const size_t statsB = (size_t)D * S * sizeof(float);           // 2 MB
  float* psum   = (float*)d_ws;
  float* psumsq = (float*)((char*)d_ws + statsB);
  float* wscale = (float*)((char*)d_ws + 2 * statsB);
  float* wshift = wscale + D;
  const size_t off_Wh = 2 * statsB + 16384;
  _Float16* Wh = (_Float16*)((char*)d_ws + off_Wh);
  _Float16* H2 = Wh + nw;
  const size_t need_h16 = off_Wh + (nw + na) * sizeof(_Float16); // ~70 MB
  const size_t need_w   = off_Wh + nw * sizeof(_Float16);        // ~6 MB

  if (ws_size >= need_h16) {
    cvt_f32_f16<<<dim3((unsigned)(nw / 8 / 256)), 256, 0, stream>>>(W, Wh, nw);
    gemm_af32<true><<<dim3(N / BN, Brows / BM), 256, 0, stream>>>(
        a, Wh, b, H2, psum, psumsq, Brows, N, K);
    bn_finalize_wave<<<dim3(D / 4), 256, 0, stream>>>(psum, psumsq, gamma, beta,
                                                      wscale, wshift,
                                                      1.0f / (float)Brows, S, D);
    bn_sparsemax_h2<<<dim3(Brows / 4), 256, 0, stream>>>(H2, p, wscale, wshift, out, D);
  } else if (ws_size >= need_w) {
    // mid-ws: H fp32 lives in d_out
    cvt_f32_f16<<<dim3((unsigned)(nw / 8 / 256)), 256, 0, stream>>>(W, Wh, nw);
    gemm_af32<false><<<dim3(N / BN, Brows / BM), 256, 0, stream>>>(
        a, Wh, b, out, psum, psumsq, Brows, N, K);
    bn_finalize_wave<<<dim3(D / 4), 256, 0, stream>>>(psum, psumsq, gamma, beta,
                                                      wscale, wshift,
                                                      1.0f / (float)Brows, S, D);
    bn_sparsemax_f32<<<dim3(Brows / 4), 256, 0, stream>>>(out, p, wscale, wshift, out, D);
  } else {
    // tiny-ws fallback: atomic stats, fp32 H in d_out, in-register cvt of A and W
    float* wsum   = (float*)d_ws;
    float* wsumsq = wsum + D;
    float* fscale = wsum + 2 * D;
    float* fshift = wsum + 3 * D;
    hipMemsetAsync(d_ws, 0, 2 * D * sizeof(float), stream);
    gemm_fallback<<<dim3(N / BN, Brows / BM), 256, 0, stream>>>(
        a, W, b, out, wsum, wsumsq, Brows, N, K);
    bn_finalize<<<dim3(D / 256), 256, 0, stream>>>(wsum, wsumsq, gamma, beta, fscale, fshift,
                                                   1.0f / (float)Brows);
    bn_sparsemax_f32<<<dim3(Brows / 4), 256, 0, stream>>>(out, p, fscale, fshift, out, D);
  }
}